// Round 27
// baseline (486.493 us; speedup 1.0000x reference)
//
#include <hip/hip_runtime.h>

#define BATCH   16384
#define IN_DIM  1024
#define OUT_DIM 4096
#define K_TOP   409
#define DELTA_W 6.5e-3f

typedef _Float16 half8  __attribute__((ext_vector_type(8)));
typedef _Float16 half4v __attribute__((ext_vector_type(4)));
typedef float    f32x4  __attribute__((ext_vector_type(4)));

// workspace layout
#define WS_XH_OFF   256
#define WS_WH_OFF   (WS_XH_OFF + (size_t)BATCH * IN_DIM * 2)
#define WS_WV_OFF   (WS_WH_OFF + (size_t)OUT_DIM * IN_DIM * 2)
#define WS_WI_OFF   (WS_WV_OFF + (size_t)OUT_DIM * 256 * 4)
#define WS_WN_OFF   (WS_WI_OFF + (size_t)OUT_DIM * 256 * 2)
#define WS_NEEDED   (WS_WV_OFF)
#define WS_NEED3    (WS_WN_OFF + (size_t)OUT_DIM * 4)

// fast values stored as f16 packed in the FIRST 8KB of each row's 16KB slot.

// ---------------------------------------------------------------- kernel A
__global__ __launch_bounds__(256)
void k_hasneg(const float* __restrict__ x, int n, int* __restrict__ flag) {
    const int stride = gridDim.x * blockDim.x;
    bool neg = false;
    for (int i = blockIdx.x * blockDim.x + threadIdx.x; i < n; i += stride)
        neg |= (x[i] < 0.0f);
    unsigned long long b = __ballot(neg);
    if (b != 0ULL && (threadIdx.x & 63) == 0)
        atomicOr(flag, 1);
}

// ---------------------------------------------------------------- kernel A2
// fused convert + CSR (r25-proven).
__global__ __launch_bounds__(256)
void k_cvt2(const float* __restrict__ x, const float* __restrict__ w,
            _Float16* __restrict__ xh, _Float16* __restrict__ wh,
            float* __restrict__ wv, unsigned short* __restrict__ wi,
            int* __restrict__ wn, int use_csr, const int* __restrict__ flag) {
    const bool bipolar = (*flag == 0);
    const int tid = threadIdx.x;
    const int lane = tid & 63;
    const int wrow = blockIdx.x * 4 + (tid >> 6);

    const float* wr = w + (size_t)wrow * IN_DIM;
    const float4* wr4 = (const float4*)(wr + lane * 16);
    _Float16* whr = wh + (size_t)wrow * IN_DIM + lane * 16;
    float4 v[4];
    int cnt = 0;
    #pragma unroll
    for (int q = 0; q < 4; ++q) {
        v[q] = wr4[q];
        ((half4v*)whr)[q] = half4v{ (_Float16)v[q].x, (_Float16)v[q].y,
                                    (_Float16)v[q].z, (_Float16)v[q].w };
        cnt += (v[q].x != 0.0f) + (v[q].y != 0.0f)
             + (v[q].z != 0.0f) + (v[q].w != 0.0f);
    }
    if (use_csr) {
        int off = cnt;
        #pragma unroll
        for (int d = 1; d < 64; d <<= 1) {
            int t = __shfl_up(off, d);
            if (lane >= d) off += t;
        }
        const int total = __shfl(off, 63);
        off -= cnt;
        float* dv = wv + (size_t)wrow * 256;
        unsigned short* di = wi + (size_t)wrow * 256;
        int pos = off;
        #pragma unroll
        for (int q = 0; q < 4; ++q) {
            #pragma unroll
            for (int e = 0; e < 4; ++e) {
                float f = (e == 0) ? v[q].x : (e == 1) ? v[q].y
                        : (e == 2) ? v[q].z : v[q].w;
                if (f != 0.0f) {
                    dv[pos] = f;
                    di[pos] = (unsigned short)(lane * 16 + q * 4 + e);
                    ++pos;
                }
            }
        }
        if (lane == 0) {
            const int n4 = (total + 3) & ~3;
            for (int i = total; i < n4 && i < 256; ++i) { dv[i] = 0.0f; di[i] = 0; }
            wn[wrow] = total;
        }
    }

    const float4* x4 = (const float4*)x;
    half4v* xh4 = (half4v*)xh;
    const int base = blockIdx.x * 4096;
    #pragma unroll
    for (int u = 0; u < 16; ++u) {
        const int idx = base + u * 256 + tid;
        float4 xv = x4[idx];
        if (bipolar) {
            xv.x = (xv.x - 0.5f) * 2.0f; xv.y = (xv.y - 0.5f) * 2.0f;
            xv.z = (xv.z - 0.5f) * 2.0f; xv.w = (xv.w - 0.5f) * 2.0f;
        }
        xh4[idx] = half4v{ (_Float16)xv.x, (_Float16)xv.y,
                           (_Float16)xv.z, (_Float16)xv.w };
    }
}

// ---------------------------------------------------------------- kernel B
// (r24-proven: 256x256 tile, 8 waves, BK=64, dbuf LDS, one barrier/K-step.)
__global__ __launch_bounds__(512, 2)
void k_gemm16(const _Float16* __restrict__ xh, const _Float16* __restrict__ wh,
              float* __restrict__ out) {
    __shared__ _Float16 Ah[2][256 * 64];
    __shared__ _Float16 Bh[2][256 * 64];
    const int tid = threadIdx.x;
    const int bm = blockIdx.x, bn = blockIdx.y;
    const int lane = tid & 63;
    const int wv = tid >> 6;
    const int wm = wv >> 2, wn = wv & 3;
    const int lr = lane & 15, lk = lane >> 4;

    const int srow = (lane >> 3);
    const int sslot = (lane & 7) ^ srow;
    f32x4 acc[8][4] = {};

    const _Float16* aS[4]; const _Float16* bS[4];
    int dOff[4];
    #pragma unroll
    for (int i = 0; i < 4; ++i) {
        const int rb = i * 64 + wv * 8;
        aS[i] = xh + (size_t)(bm * 256 + rb + srow) * IN_DIM + sslot * 8;
        bS[i] = wh + (size_t)(bn * 256 + rb + srow) * IN_DIM + sslot * 8;
        dOff[i] = rb * 64;
    }

    #pragma unroll
    for (int i = 0; i < 4; ++i) {
        __builtin_amdgcn_global_load_lds((const __attribute__((address_space(1))) void*)(aS[i]), (__attribute__((address_space(3))) void*)&Ah[0][dOff[i]], 16, 0, 0);
        __builtin_amdgcn_global_load_lds((const __attribute__((address_space(1))) void*)(bS[i]), (__attribute__((address_space(3))) void*)&Bh[0][dOff[i]], 16, 0, 0);
    }
    __syncthreads();

    int cur = 0;
    #pragma unroll 1
    for (int t = 0; t < 16; ++t) {
        if (t < 15) {
            const int kt = (t + 1) * 64;
            #pragma unroll
            for (int i = 0; i < 4; ++i) {
                __builtin_amdgcn_global_load_lds((const __attribute__((address_space(1))) void*)(aS[i] + kt), (__attribute__((address_space(3))) void*)&Ah[cur ^ 1][dOff[i]], 16, 0, 0);
                __builtin_amdgcn_global_load_lds((const __attribute__((address_space(1))) void*)(bS[i] + kt), (__attribute__((address_space(3))) void*)&Bh[cur ^ 1][dOff[i]], 16, 0, 0);
            }
        }
        #pragma unroll
        for (int h = 0; h < 2; ++h) {
            half8 bf[4];
            #pragma unroll
            for (int j = 0; j < 4; ++j) {
                const int rbv = wn * 64 + j * 16 + lr;
                const int sb = (h * 4 + lk) ^ (rbv & 7);
                bf[j] = *(const half8*)&Bh[cur][rbv * 64 + (sb << 3)];
            }
            #pragma unroll
            for (int hf = 0; hf < 2; ++hf) {
                half8 af[4];
                #pragma unroll
                for (int i = 0; i < 4; ++i) {
                    const int ra = wm * 128 + (hf * 4 + i) * 16 + lr;
                    const int sa = (h * 4 + lk) ^ (ra & 7);
                    af[i] = *(const half8*)&Ah[cur][ra * 64 + (sa << 3)];
                }
                #pragma unroll
                for (int i = 0; i < 4; ++i)
                    #pragma unroll
                    for (int j = 0; j < 4; ++j)
                        acc[hf * 4 + i][j] = __builtin_amdgcn_mfma_f32_16x16x32_f16(
                            af[i], bf[j], acc[hf * 4 + i][j], 0, 0, 0);
            }
        }
        __syncthreads();
        cur ^= 1;
    }
    #pragma unroll
    for (int i = 0; i < 8; ++i)
        #pragma unroll
        for (int j = 0; j < 4; ++j)
            #pragma unroll
            for (int q = 0; q < 4; ++q) {
                const int row = bm * 256 + wm * 128 + i * 16 + lk * 4 + q;
                const int col = bn * 256 + wn * 64 + j * 16 + lr;
                _Float16* fo = (_Float16*)((char*)out + (size_t)row * OUT_DIM * 4);
                fo[col] = (_Float16)acc[i][j][q];
            }
}

// ---------------------------------------------------------------- kernel C
// FUSED select, 512 threads (8 elems/thread): early unconditional x-stage
// (overlaps histogram), cached coarse buckets, 2-level histogram, classify,
// CSR replica chains (EXACT r13 order), tie-inclusive rank, encode, norm,
// nontemporal f32 write. Selection math bit-identical to r25.
__global__ __launch_bounds__(512)
void k_self(float* __restrict__ po, const float* __restrict__ x,
            const float* __restrict__ wvals, const unsigned short* __restrict__ widx,
            const int* __restrict__ wn, const float* __restrict__ wfull,
            int use_csr, const int* __restrict__ flag) {
    __shared__ unsigned int bins[256];
    __shared__ float fred[8];
    __shared__ unsigned int wsum[4];
    __shared__ int ired[8];
    __shared__ int s_b, s_b2;
    __shared__ unsigned int s_slot, s_hi1;
    __shared__ int bcol[64];
    __shared__ float bnp[64];
    __shared__ unsigned char bsel[64];
    __shared__ float xs[IN_DIM];

    const int row = blockIdx.x;
    const int tid = threadIdx.x;
    const int lane = tid & 63, wq = tid >> 6;
    const _Float16* fr = (const _Float16*)((const char*)po + (size_t)row * OUT_DIM * 4);

    // early x-stage (need is ~always true; overlaps with histogram phases)
    const bool bipolar = (*flag == 0);
    if (tid < 256) {
        float4 xv = ((const float4*)(x + (size_t)row * IN_DIM))[tid];
        if (bipolar) {
            xv.x = __fmul_rn(__fadd_rn(xv.x, -0.5f), 2.0f);
            xv.y = __fmul_rn(__fadd_rn(xv.y, -0.5f), 2.0f);
            xv.z = __fmul_rn(__fadd_rn(xv.z, -0.5f), 2.0f);
            xv.w = __fmul_rn(__fadd_rn(xv.w, -0.5f), 2.0f);
        }
        ((float4*)xs)[tid] = xv;
    }

    half8 h0 = *(const half8*)&fr[tid * 8];
    float fv[8];
    int bb[8];
    float vmax = -1e30f;
    #pragma unroll
    for (int e = 0; e < 8; ++e) {
        fv[e] = (float)h0[e];
        vmax = fmaxf(vmax, fv[e]);
    }
    #pragma unroll
    for (int off = 32; off > 0; off >>= 1)
        vmax = fmaxf(vmax, __shfl_xor(vmax, off));
    if (lane == 0) fred[wq] = vmax;
    if (tid < 256) bins[tid] = 0;
    if (tid == 0) { s_slot = 0; s_b = 0; s_b2 = 0; s_hi1 = 0; }
    __syncthreads();
    vmax = fred[0];
    #pragma unroll
    for (int q = 1; q < 8; ++q) vmax = fmaxf(vmax, fred[q]);
    vmax = fmaxf(vmax, 1e-6f);
    const float scale1 = 256.0f / vmax;
    const float invscale1 = vmax * (1.0f / 256.0f);

    // pass 1 (cache coarse bucket)
    #pragma unroll
    for (int e = 0; e < 8; ++e) {
        float f = fv[e];
        int b = -1;
        if (f > 0.0f) {
            b = (int)(f * scale1);
            if (b > 255) b = 255;
            atomicAdd(&bins[b], 1u);
        }
        bb[e] = b;
    }
    __syncthreads();
    {
        unsigned int c = 0, sc = 0;
        if (tid < 256) {
            c = bins[255 - tid];
            sc = c;
            #pragma unroll
            for (int off = 1; off < 64; off <<= 1) {
                unsigned int t2 = __shfl_up(sc, off);
                if (lane >= off) sc += t2;
            }
            if (lane == 63) wsum[wq] = sc;
        }
        __syncthreads();
        if (tid < 256) {
            for (int q = 0; q < wq; ++q) sc += wsum[q];
            if ((int)sc >= K_TOP && (int)(sc - c) < K_TOP) {
                s_b = 255 - tid;
                s_hi1 = sc - c;
            }
        }
    }
    __syncthreads();
    const int b1 = s_b;
    const unsigned int hi1 = s_hi1;
    const float blo = (float)b1 * invscale1;
    const float scale2 = scale1 * 256.0f;
    const float s2w = invscale1 * (1.0f / 256.0f);

    if (tid < 256) bins[tid] = 0;
    __syncthreads();
    #pragma unroll
    for (int e = 0; e < 8; ++e) {
        if (bb[e] == b1) {
            int b2 = (int)((fv[e] - blo) * scale2);
            if (b2 < 0) b2 = 0;
            if (b2 > 255) b2 = 255;
            atomicAdd(&bins[b2], 1u);
        }
    }
    __syncthreads();
    {
        unsigned int c = 0, sc = 0;
        if (tid < 256) {
            c = bins[255 - tid];
            sc = c;
            #pragma unroll
            for (int off = 1; off < 64; off <<= 1) {
                unsigned int t2 = __shfl_up(sc, off);
                if (lane >= off) sc += t2;
            }
            if (lane == 63) wsum[wq] = sc;
        }
        __syncthreads();
        if (tid < 256) {
            for (int q = 0; q < wq; ++q) sc += wsum[q];
            if ((int)(hi1 + sc) >= K_TOP && (int)(hi1 + sc - c) < K_TOP)
                s_b2 = 255 - tid;
        }
    }
    __syncthreads();
    const float thi = blo + (float)(s_b2 + 1) * s2w + DELTA_W;
    const float tlo = blo + (float)s_b2 * s2w - DELTA_W;

    // classify
    int hic = 0;
    #pragma unroll
    for (int e = 0; e < 8; ++e) {
        float f = fv[e];
        if (f > thi) ++hic;
        else if (f >= tlo) {
            unsigned int p = atomicAdd(&s_slot, 1u);
            if (p < 64) bcol[p] = tid * 8 + e;
        }
    }
    #pragma unroll
    for (int off = 32; off > 0; off >>= 1)
        hic += __shfl_xor(hic, off);
    if (lane == 0) ired[wq] = hic;
    __syncthreads();
    int hi = ired[0];
    #pragma unroll
    for (int q = 1; q < 8; ++q) hi += ired[q];
    const int nb = (int)s_slot;
    const int nbc = nb > 64 ? 64 : nb;
    int krem = K_TOP - hi; if (krem > nb) krem = nb; if (krem < 0) krem = 0;
    const bool need = (nb != krem);          // uniform

    if (need) {
        if (tid < nbc) {
            const int col = bcol[tid];
            float p = 0.0f;
            if (use_csr) {
                const int n4 = (wn[col] + 3) >> 2;
                const float4* v4 = (const float4*)(wvals + (size_t)col * 256);
                const ushort4* i4 = (const ushort4*)(widx + (size_t)col * 256);
                #pragma unroll 2
                for (int i = 0; i < n4; ++i) {
                    float4 vv = v4[i];
                    ushort4 ii = i4[i];
                    p = __fmaf_rn(xs[ii.x], vv.x, p);
                    p = __fmaf_rn(xs[ii.y], vv.y, p);
                    p = __fmaf_rn(xs[ii.z], vv.z, p);
                    p = __fmaf_rn(xs[ii.w], vv.w, p);
                }
            } else {
                const float4* wr4 = (const float4*)(wfull + (size_t)col * IN_DIM);
                const float4* xs4 = (const float4*)xs;
                #pragma unroll 4
                for (int i = 0; i < IN_DIM / 4; ++i) {
                    float4 xq = xs4[i];
                    float4 wq2 = wr4[i];
                    p = __fmaf_rn(xq.x, wq2.x, p);
                    p = __fmaf_rn(xq.y, wq2.y, p);
                    p = __fmaf_rn(xq.z, wq2.z, p);
                    p = __fmaf_rn(xq.w, wq2.w, p);
                }
            }
            bnp[tid] = p;
        }
        __syncthreads();
        if (tid < nbc) {
            const float v = bnp[tid];
            int gc = 0;
            for (int l = 0; l < nbc; ++l) gc += (bnp[l] > v);
            bsel[tid] = (gc < krem) ? 1 : 0;
        }
        __syncthreads();
    }

    // encode, norm, nontemporal write
    float ov[8];
    float nrm2 = 0.0f;
    #pragma unroll
    for (int e = 0; e < 8; ++e) {
        float f = fv[e];
        const int j = tid * 8 + e;
        bool sel = (f > thi);
        float val = f;
        if (!sel && f >= tlo) {
            if (!need) sel = true;
            else {
                for (int m = 0; m < nbc; ++m)
                    if (bcol[m] == j) {
                        sel = (bsel[m] != 0);
                        val = bnp[m];
                        break;
                    }
            }
        }
        float eo = (sel && val > 0.0f) ? val : 0.0f;
        ov[e] = eo;
        nrm2 += eo * eo;
    }
    #pragma unroll
    for (int off = 32; off > 0; off >>= 1)
        nrm2 += __shfl_xor(nrm2, off);
    if (lane == 0) fred[wq] = nrm2;
    __syncthreads();
    float total = fred[0];
    #pragma unroll
    for (int q = 1; q < 8; ++q) total += fred[q];
    const float inv = 1.0f / fmaxf(sqrtf(total), 1e-12f);

    f32x4* p4 = (f32x4*)(po + (size_t)row * OUT_DIM);
    f32x4 o0 = { ov[0] * inv, ov[1] * inv, ov[2] * inv, ov[3] * inv };
    f32x4 o1 = { ov[4] * inv, ov[5] * inv, ov[6] * inv, ov[7] * inv };
    __builtin_nontemporal_store(o0, &p4[tid * 2]);
    __builtin_nontemporal_store(o1, &p4[tid * 2 + 1]);
}

// ---------------------------------------------------------------- launch
extern "C" void kernel_launch(void* const* d_in, const int* in_sizes, int n_in,
                              void* d_out, int out_size, void* d_ws, size_t ws_size,
                              hipStream_t stream) {
    const float* x = (const float*)d_in[0];
    const float* w = (const float*)d_in[1];
    float* out = (float*)d_out;
    int* flag = (int*)d_ws;
    const int use_csr = (ws_size >= WS_NEED3) ? 1 : 0;

    hipMemsetAsync(flag, 0, sizeof(int), stream);
    k_hasneg<<<2048, 256, 0, stream>>>(x, BATCH * IN_DIM, flag);

    _Float16* xh = (_Float16*)((char*)d_ws + WS_XH_OFF);
    _Float16* wh = (_Float16*)((char*)d_ws + WS_WH_OFF);
    float* wv = (float*)((char*)d_ws + WS_WV_OFF);
    unsigned short* wi = (unsigned short*)((char*)d_ws + WS_WI_OFF);
    int* wn = (int*)((char*)d_ws + WS_WN_OFF);

    k_cvt2<<<OUT_DIM / 4, 256, 0, stream>>>(x, w, xh, wh, wv, wi, wn,
                                            use_csr, flag);
    dim3 g(BATCH / 256, OUT_DIM / 256);
    k_gemm16<<<g, 512, 0, stream>>>(xh, wh, out);

    k_self<<<BATCH, 512, 0, stream>>>(out, x, wv, wi, wn, w, use_csr, flag);
}

// Round 28
// 420.816 us; speedup vs baseline: 1.1561x; 1.1561x over previous
//
#include <hip/hip_runtime.h>

#define BATCH   16384
#define IN_DIM  1024
#define OUT_DIM 4096
#define K_TOP   409
#define DELTA_W 6.5e-3f

typedef _Float16 half8  __attribute__((ext_vector_type(8)));
typedef _Float16 half4v __attribute__((ext_vector_type(4)));
typedef float    f32x4  __attribute__((ext_vector_type(4)));

// workspace layout
#define WS_XH_OFF   256
#define WS_WH_OFF   (WS_XH_OFF + (size_t)BATCH * IN_DIM * 2)
#define WS_WV_OFF   (WS_WH_OFF + (size_t)OUT_DIM * IN_DIM * 2)
#define WS_WI_OFF   (WS_WV_OFF + (size_t)OUT_DIM * 256 * 4)
#define WS_WN_OFF   (WS_WI_OFF + (size_t)OUT_DIM * 256 * 2)
#define WS_NEEDED   (WS_WV_OFF)
#define WS_NEED3    (WS_WN_OFF + (size_t)OUT_DIM * 4)

// fast values stored as f16 packed in the FIRST 8KB of each row's 16KB slot.

// ---------------------------------------------------------------- kernel A
__global__ __launch_bounds__(256)
void k_hasneg(const float* __restrict__ x, int n, int* __restrict__ flag) {
    const int stride = gridDim.x * blockDim.x;
    bool neg = false;
    for (int i = blockIdx.x * blockDim.x + threadIdx.x; i < n; i += stride)
        neg |= (x[i] < 0.0f);
    unsigned long long b = __ballot(neg);
    if (b != 0ULL && (threadIdx.x & 63) == 0)
        atomicOr(flag, 1);
}

// ---------------------------------------------------------------- kernel A2
// fused convert + CSR (r25-proven).
__global__ __launch_bounds__(256)
void k_cvt2(const float* __restrict__ x, const float* __restrict__ w,
            _Float16* __restrict__ xh, _Float16* __restrict__ wh,
            float* __restrict__ wv, unsigned short* __restrict__ wi,
            int* __restrict__ wn, int use_csr, const int* __restrict__ flag) {
    const bool bipolar = (*flag == 0);
    const int tid = threadIdx.x;
    const int lane = tid & 63;
    const int wrow = blockIdx.x * 4 + (tid >> 6);

    const float* wr = w + (size_t)wrow * IN_DIM;
    const float4* wr4 = (const float4*)(wr + lane * 16);
    _Float16* whr = wh + (size_t)wrow * IN_DIM + lane * 16;
    float4 v[4];
    int cnt = 0;
    #pragma unroll
    for (int q = 0; q < 4; ++q) {
        v[q] = wr4[q];
        ((half4v*)whr)[q] = half4v{ (_Float16)v[q].x, (_Float16)v[q].y,
                                    (_Float16)v[q].z, (_Float16)v[q].w };
        cnt += (v[q].x != 0.0f) + (v[q].y != 0.0f)
             + (v[q].z != 0.0f) + (v[q].w != 0.0f);
    }
    if (use_csr) {
        int off = cnt;
        #pragma unroll
        for (int d = 1; d < 64; d <<= 1) {
            int t = __shfl_up(off, d);
            if (lane >= d) off += t;
        }
        const int total = __shfl(off, 63);
        off -= cnt;
        float* dv = wv + (size_t)wrow * 256;
        unsigned short* di = wi + (size_t)wrow * 256;
        int pos = off;
        #pragma unroll
        for (int q = 0; q < 4; ++q) {
            #pragma unroll
            for (int e = 0; e < 4; ++e) {
                float f = (e == 0) ? v[q].x : (e == 1) ? v[q].y
                        : (e == 2) ? v[q].z : v[q].w;
                if (f != 0.0f) {
                    dv[pos] = f;
                    di[pos] = (unsigned short)(lane * 16 + q * 4 + e);
                    ++pos;
                }
            }
        }
        if (lane == 0) {
            const int n4 = (total + 3) & ~3;
            for (int i = total; i < n4 && i < 256; ++i) { dv[i] = 0.0f; di[i] = 0; }
            wn[wrow] = total;
        }
    }

    const float4* x4 = (const float4*)x;
    half4v* xh4 = (half4v*)xh;
    const int base = blockIdx.x * 4096;
    #pragma unroll
    for (int u = 0; u < 16; ++u) {
        const int idx = base + u * 256 + tid;
        float4 xv = x4[idx];
        if (bipolar) {
            xv.x = (xv.x - 0.5f) * 2.0f; xv.y = (xv.y - 0.5f) * 2.0f;
            xv.z = (xv.z - 0.5f) * 2.0f; xv.w = (xv.w - 0.5f) * 2.0f;
        }
        xh4[idx] = half4v{ (_Float16)xv.x, (_Float16)xv.y,
                           (_Float16)xv.z, (_Float16)xv.w };
    }
}

// ---------------------------------------------------------------- kernel B
// (r24-proven: 256x256 tile, 8 waves, BK=64, dbuf LDS, one barrier/K-step.)
__global__ __launch_bounds__(512, 2)
void k_gemm16(const _Float16* __restrict__ xh, const _Float16* __restrict__ wh,
              float* __restrict__ out) {
    __shared__ _Float16 Ah[2][256 * 64];
    __shared__ _Float16 Bh[2][256 * 64];
    const int tid = threadIdx.x;
    const int bm = blockIdx.x, bn = blockIdx.y;
    const int lane = tid & 63;
    const int wv = tid >> 6;
    const int wm = wv >> 2, wn = wv & 3;
    const int lr = lane & 15, lk = lane >> 4;

    const int srow = (lane >> 3);
    const int sslot = (lane & 7) ^ srow;
    f32x4 acc[8][4] = {};

    const _Float16* aS[4]; const _Float16* bS[4];
    int dOff[4];
    #pragma unroll
    for (int i = 0; i < 4; ++i) {
        const int rb = i * 64 + wv * 8;
        aS[i] = xh + (size_t)(bm * 256 + rb + srow) * IN_DIM + sslot * 8;
        bS[i] = wh + (size_t)(bn * 256 + rb + srow) * IN_DIM + sslot * 8;
        dOff[i] = rb * 64;
    }

    #pragma unroll
    for (int i = 0; i < 4; ++i) {
        __builtin_amdgcn_global_load_lds((const __attribute__((address_space(1))) void*)(aS[i]), (__attribute__((address_space(3))) void*)&Ah[0][dOff[i]], 16, 0, 0);
        __builtin_amdgcn_global_load_lds((const __attribute__((address_space(1))) void*)(bS[i]), (__attribute__((address_space(3))) void*)&Bh[0][dOff[i]], 16, 0, 0);
    }
    __syncthreads();

    int cur = 0;
    #pragma unroll 1
    for (int t = 0; t < 16; ++t) {
        if (t < 15) {
            const int kt = (t + 1) * 64;
            #pragma unroll
            for (int i = 0; i < 4; ++i) {
                __builtin_amdgcn_global_load_lds((const __attribute__((address_space(1))) void*)(aS[i] + kt), (__attribute__((address_space(3))) void*)&Ah[cur ^ 1][dOff[i]], 16, 0, 0);
                __builtin_amdgcn_global_load_lds((const __attribute__((address_space(1))) void*)(bS[i] + kt), (__attribute__((address_space(3))) void*)&Bh[cur ^ 1][dOff[i]], 16, 0, 0);
            }
        }
        #pragma unroll
        for (int h = 0; h < 2; ++h) {
            half8 bf[4];
            #pragma unroll
            for (int j = 0; j < 4; ++j) {
                const int rbv = wn * 64 + j * 16 + lr;
                const int sb = (h * 4 + lk) ^ (rbv & 7);
                bf[j] = *(const half8*)&Bh[cur][rbv * 64 + (sb << 3)];
            }
            #pragma unroll
            for (int hf = 0; hf < 2; ++hf) {
                half8 af[4];
                #pragma unroll
                for (int i = 0; i < 4; ++i) {
                    const int ra = wm * 128 + (hf * 4 + i) * 16 + lr;
                    const int sa = (h * 4 + lk) ^ (ra & 7);
                    af[i] = *(const half8*)&Ah[cur][ra * 64 + (sa << 3)];
                }
                #pragma unroll
                for (int i = 0; i < 4; ++i)
                    #pragma unroll
                    for (int j = 0; j < 4; ++j)
                        acc[hf * 4 + i][j] = __builtin_amdgcn_mfma_f32_16x16x32_f16(
                            af[i], bf[j], acc[hf * 4 + i][j], 0, 0, 0);
            }
        }
        __syncthreads();
        cur ^= 1;
    }
    #pragma unroll
    for (int i = 0; i < 8; ++i)
        #pragma unroll
        for (int j = 0; j < 4; ++j)
            #pragma unroll
            for (int q = 0; q < 4; ++q) {
                const int row = bm * 256 + wm * 128 + i * 16 + lk * 4 + q;
                const int col = bn * 256 + wn * 64 + j * 16 + lr;
                _Float16* fo = (_Float16*)((char*)out + (size_t)row * OUT_DIM * 4);
                fo[col] = (_Float16)acc[i][j][q];
            }
}

// ---------------------------------------------------------------- kernel C
// FUSED select, 256 threads (r25-proven shape; r27's 512-thread variant
// regressed from half-idle barriers). Grafts: early unconditional x-stage
// (overlaps histogram), cached coarse buckets, nontemporal final stores.
// Selection math bit-identical to r25.
__global__ __launch_bounds__(256)
void k_self(float* __restrict__ po, const float* __restrict__ x,
            const float* __restrict__ wvals, const unsigned short* __restrict__ widx,
            const int* __restrict__ wn, const float* __restrict__ wfull,
            int use_csr, const int* __restrict__ flag) {
    __shared__ unsigned int bins[256];
    __shared__ float fred[4];
    __shared__ unsigned int wsum[4];
    __shared__ int ired[4];
    __shared__ int s_b, s_b2;
    __shared__ unsigned int s_slot, s_hi1;
    __shared__ int bcol[64];
    __shared__ float bnp[64];
    __shared__ unsigned char bsel[64];
    __shared__ float xs[IN_DIM];

    const int row = blockIdx.x;
    const int tid = threadIdx.x;
    const int lane = tid & 63, wq = tid >> 6;
    const _Float16* fr = (const _Float16*)((const char*)po + (size_t)row * OUT_DIM * 4);

    // early x-stage: need is ~always true; overlaps the histogram phases.
    const bool bipolar = (*flag == 0);
    {
        float4 xv = ((const float4*)(x + (size_t)row * IN_DIM))[tid];
        if (bipolar) {
            xv.x = __fmul_rn(__fadd_rn(xv.x, -0.5f), 2.0f);
            xv.y = __fmul_rn(__fadd_rn(xv.y, -0.5f), 2.0f);
            xv.z = __fmul_rn(__fadd_rn(xv.z, -0.5f), 2.0f);
            xv.w = __fmul_rn(__fadd_rn(xv.w, -0.5f), 2.0f);
        }
        ((float4*)xs)[tid] = xv;
    }

    half8 h0 = *(const half8*)&fr[tid * 8];
    half8 h1 = *(const half8*)&fr[2048 + tid * 8];
    float fv[16];
    int bb[16];
    float vmax = -1e30f;
    #pragma unroll
    for (int e = 0; e < 8; ++e) {
        fv[e] = (float)h0[e];
        fv[8 + e] = (float)h1[e];
        vmax = fmaxf(vmax, fmaxf(fv[e], fv[8 + e]));
    }
    #pragma unroll
    for (int off = 32; off > 0; off >>= 1)
        vmax = fmaxf(vmax, __shfl_xor(vmax, off));
    if (lane == 0) fred[wq] = vmax;
    bins[tid] = 0;
    if (tid == 0) { s_slot = 0; s_b = 0; s_b2 = 0; s_hi1 = 0; }
    __syncthreads();
    vmax = fmaxf(fmaxf(fmaxf(fred[0], fred[1]), fmaxf(fred[2], fred[3])), 1e-6f);
    const float scale1 = 256.0f / vmax;
    const float invscale1 = vmax * (1.0f / 256.0f);

    // pass 1 (cache coarse bucket)
    #pragma unroll
    for (int e = 0; e < 16; ++e) {
        float f = fv[e];
        int b = -1;
        if (f > 0.0f) {
            b = (int)(f * scale1);
            if (b > 255) b = 255;
            atomicAdd(&bins[b], 1u);
        }
        bb[e] = b;
    }
    __syncthreads();
    {
        const unsigned int c = bins[255 - tid];
        unsigned int sc = c;
        #pragma unroll
        for (int off = 1; off < 64; off <<= 1) {
            unsigned int t2 = __shfl_up(sc, off);
            if (lane >= off) sc += t2;
        }
        if (lane == 63) wsum[wq] = sc;
        __syncthreads();
        for (int q = 0; q < wq; ++q) sc += wsum[q];
        if ((int)sc >= K_TOP && (int)(sc - c) < K_TOP) {
            s_b = 255 - tid;
            s_hi1 = sc - c;
        }
    }
    __syncthreads();
    const int b1 = s_b;
    const unsigned int hi1 = s_hi1;
    const float blo = (float)b1 * invscale1;
    const float scale2 = scale1 * 256.0f;
    const float s2w = invscale1 * (1.0f / 256.0f);

    bins[tid] = 0;
    __syncthreads();
    #pragma unroll
    for (int e = 0; e < 16; ++e) {
        if (bb[e] == b1) {
            int b2 = (int)((fv[e] - blo) * scale2);
            if (b2 < 0) b2 = 0;
            if (b2 > 255) b2 = 255;
            atomicAdd(&bins[b2], 1u);
        }
    }
    __syncthreads();
    {
        const unsigned int c = bins[255 - tid];
        unsigned int sc = c;
        #pragma unroll
        for (int off = 1; off < 64; off <<= 1) {
            unsigned int t2 = __shfl_up(sc, off);
            if (lane >= off) sc += t2;
        }
        if (lane == 63) wsum[wq] = sc;
        __syncthreads();
        for (int q = 0; q < wq; ++q) sc += wsum[q];
        if ((int)(hi1 + sc) >= K_TOP && (int)(hi1 + sc - c) < K_TOP)
            s_b2 = 255 - tid;
    }
    __syncthreads();
    const float thi = blo + (float)(s_b2 + 1) * s2w + DELTA_W;
    const float tlo = blo + (float)s_b2 * s2w - DELTA_W;

    // classify: per-thread hi count (reduced), atomic window slots
    int hic = 0;
    #pragma unroll
    for (int e = 0; e < 16; ++e) {
        float f = fv[e];
        if (f > thi) ++hic;
        else if (f >= tlo) {
            unsigned int p = atomicAdd(&s_slot, 1u);
            const int j = (e < 8) ? (tid * 8 + e) : (2048 + tid * 8 + e - 8);
            if (p < 64) bcol[p] = j;
        }
    }
    #pragma unroll
    for (int off = 32; off > 0; off >>= 1)
        hic += __shfl_xor(hic, off);
    if (lane == 0) ired[wq] = hic;
    __syncthreads();
    const int hi = ired[0] + ired[1] + ired[2] + ired[3];
    const int nb = (int)s_slot;
    const int nbc = nb > 64 ? 64 : nb;
    int krem = K_TOP - hi; if (krem > nb) krem = nb; if (krem < 0) krem = 0;
    const bool need = (nb != krem);          // uniform

    if (need) {
        if (tid < nbc) {
            const int col = bcol[tid];
            float p = 0.0f;
            if (use_csr) {
                const int n4 = (wn[col] + 3) >> 2;
                const float4* v4 = (const float4*)(wvals + (size_t)col * 256);
                const ushort4* i4 = (const ushort4*)(widx + (size_t)col * 256);
                #pragma unroll 2
                for (int i = 0; i < n4; ++i) {
                    float4 vv = v4[i];
                    ushort4 ii = i4[i];
                    p = __fmaf_rn(xs[ii.x], vv.x, p);
                    p = __fmaf_rn(xs[ii.y], vv.y, p);
                    p = __fmaf_rn(xs[ii.z], vv.z, p);
                    p = __fmaf_rn(xs[ii.w], vv.w, p);
                }
            } else {
                const float4* wr4 = (const float4*)(wfull + (size_t)col * IN_DIM);
                const float4* xs4 = (const float4*)xs;
                #pragma unroll 4
                for (int i = 0; i < IN_DIM / 4; ++i) {
                    float4 xq = xs4[i];
                    float4 wq2 = wr4[i];
                    p = __fmaf_rn(xq.x, wq2.x, p);
                    p = __fmaf_rn(xq.y, wq2.y, p);
                    p = __fmaf_rn(xq.z, wq2.z, p);
                    p = __fmaf_rn(xq.w, wq2.w, p);
                }
            }
            bnp[tid] = p;
        }
        __syncthreads();
        if (tid < nbc) {
            const float v = bnp[tid];
            int gc = 0;
            for (int l = 0; l < nbc; ++l) gc += (bnp[l] > v);
            bsel[tid] = (gc < krem) ? 1 : 0;
        }
        __syncthreads();
    }

    // encode, norm, nontemporal write
    float ov[16];
    float nrm2 = 0.0f;
    #pragma unroll
    for (int e = 0; e < 16; ++e) {
        float f = fv[e];
        const int j = (e < 8) ? (tid * 8 + e) : (2048 + tid * 8 + e - 8);
        bool sel = (f > thi);
        float val = f;
        if (!sel && f >= tlo) {
            if (!need) sel = true;
            else {
                for (int m = 0; m < nbc; ++m)
                    if (bcol[m] == j) {
                        sel = (bsel[m] != 0);
                        val = bnp[m];
                        break;
                    }
            }
        }
        float eo = (sel && val > 0.0f) ? val : 0.0f;
        ov[e] = eo;
        nrm2 += eo * eo;
    }
    #pragma unroll
    for (int off = 32; off > 0; off >>= 1)
        nrm2 += __shfl_xor(nrm2, off);
    if (lane == 0) fred[wq] = nrm2;
    __syncthreads();
    const float total = fred[0] + fred[1] + fred[2] + fred[3];
    const float inv = 1.0f / fmaxf(sqrtf(total), 1e-12f);

    f32x4* p4 = (f32x4*)(po + (size_t)row * OUT_DIM);
    #pragma unroll
    for (int h = 0; h < 2; ++h) {
        const int base = (h == 0) ? 0 : 8;
        const int fi = (h == 0) ? (tid * 2) : (512 + tid * 2);
        f32x4 o0 = { ov[base + 0] * inv, ov[base + 1] * inv,
                     ov[base + 2] * inv, ov[base + 3] * inv };
        f32x4 o1 = { ov[base + 4] * inv, ov[base + 5] * inv,
                     ov[base + 6] * inv, ov[base + 7] * inv };
        __builtin_nontemporal_store(o0, &p4[fi]);
        __builtin_nontemporal_store(o1, &p4[fi + 1]);
    }
}

// ---------------------------------------------------------------- launch
extern "C" void kernel_launch(void* const* d_in, const int* in_sizes, int n_in,
                              void* d_out, int out_size, void* d_ws, size_t ws_size,
                              hipStream_t stream) {
    const float* x = (const float*)d_in[0];
    const float* w = (const float*)d_in[1];
    float* out = (float*)d_out;
    int* flag = (int*)d_ws;
    const int use_csr = (ws_size >= WS_NEED3) ? 1 : 0;

    hipMemsetAsync(flag, 0, sizeof(int), stream);
    k_hasneg<<<2048, 256, 0, stream>>>(x, BATCH * IN_DIM, flag);

    _Float16* xh = (_Float16*)((char*)d_ws + WS_XH_OFF);
    _Float16* wh = (_Float16*)((char*)d_ws + WS_WH_OFF);
    float* wv = (float*)((char*)d_ws + WS_WV_OFF);
    unsigned short* wi = (unsigned short*)((char*)d_ws + WS_WI_OFF);
    int* wn = (int*)((char*)d_ws + WS_WN_OFF);

    k_cvt2<<<OUT_DIM / 4, 256, 0, stream>>>(x, w, xh, wh, wv, wi, wn,
                                            use_csr, flag);
    dim3 g(BATCH / 256, OUT_DIM / 256);
    k_gemm16<<<g, 512, 0, stream>>>(xh, wh, out);

    k_self<<<BATCH, 256, 0, stream>>>(out, x, wv, wi, wn, w, use_csr, flag);
}